// Round 3
// baseline (76.226 us; speedup 1.0000x reference)
//
#include <hip/hip_runtime.h>

#define B_    1024
#define NIN_  128
#define NOUT_ 128
#define N_    512
#define EPS_  1e-5f

typedef float f32x4 __attribute__((ext_vector_type(4)));

// k0: zero the 256 stat accumulators (ws is poisoned 0xAA; must zero each call)
__global__ __launch_bounds__(256) void k0_zero(float* __restrict__ acc)
{
    acc[threadIdx.x] = 0.0f;
}

// k1: masked reduce over n + fused 128x128 linear + atomic batch-stats
// grid = B_, block = 512
__global__ __launch_bounds__(512) void k1_maskreduce_linear(
    const int* __restrict__ A, const float* __restrict__ x,
    const float* __restrict__ W, const float* __restrict__ bias,
    const int* __restrict__ dil_p, float* __restrict__ h,
    float* __restrict__ accS, float* __restrict__ accQ,
    float* __restrict__ outA)
{
    __shared__ float m[N_];
    __shared__ float s[NIN_];
    const int b = blockIdx.x;
    const int t = threadIdx.x;
    const int dil = *dil_p;

    // Load A row, build mask in LDS, and emit output 0 (A as float, nt store)
    const int* Arow = A + (size_t)b * N_;
    float* oA = outA + (size_t)b * N_;
    {
        int n = t;               // 512 threads, N_=512: one element each
        int a = Arow[n];
        m[n] = (a == dil || a == -1) ? 1.0f : 0.0f;
        __builtin_nontemporal_store((float)a, &oA[n]);
    }
    __syncthreads();

    const int wave = t >> 6;
    const int lane = t & 63;

    // Per-lane mask registers: lane l covers n in [4l,4l+4) and [256+4l,4l+4)
    float mA[4], mB[4];
    #pragma unroll
    for (int j = 0; j < 4; ++j) {
        mA[j] = m[lane * 4 + j];
        mB[j] = m[256 + lane * 4 + j];
    }

    // 8 waves x 16 channels; two fully-contiguous 1KB wave loads per channel.
    // Non-temporal: x is 256 MB stream-once data, keep it out of L2.
    for (int i = wave; i < NIN_; i += 8) {
        const float* row = x + ((size_t)b * NIN_ + i) * N_;
        f32x4 v0 = __builtin_nontemporal_load((const f32x4*)(row + lane * 4));
        f32x4 v1 = __builtin_nontemporal_load((const f32x4*)(row + 256 + lane * 4));
        float acc = v0.x * mA[0] + v0.y * mA[1] + v0.z * mA[2] + v0.w * mA[3]
                  + v1.x * mB[0] + v1.y * mB[1] + v1.z * mB[2] + v1.w * mB[3];
        #pragma unroll
        for (int off = 32; off > 0; off >>= 1)
            acc += __shfl_xor(acc, off, 64);
        if (lane == 0) s[i] = acc;
    }
    __syncthreads();

    // h[b,o] = bias[o] + sum_i W[o,i] * s[i]; feed batch stats via TCC atomics
    if (t < NOUT_) {
        const float* Wr = W + (size_t)t * NIN_;
        float acc = bias[t];
        #pragma unroll 8
        for (int i = 0; i < NIN_; ++i) acc += Wr[i] * s[i];
        h[(size_t)b * NOUT_ + t] = acc;
        atomicAdd(&accS[t], acc);
        atomicAdd(&accQ[t], acc * acc);
    }
}

// k3: normalize + ReLU, stats computed inline from accumulators
// grid = B_*NOUT_/256, block = 256
__global__ __launch_bounds__(256) void k3_norm(
    const float* __restrict__ h, const float* __restrict__ accS,
    const float* __restrict__ accQ, const float* __restrict__ gamma,
    const float* __restrict__ beta, float* __restrict__ outF)
{
    const int idx = blockIdx.x * 256 + threadIdx.x;
    const int o = idx & (NOUT_ - 1);
    float mean = accS[o] * (1.0f / B_);
    float var  = accQ[o] * (1.0f / B_) - mean * mean;   // biased, training mode
    float sc   = gamma[o] * rsqrtf(var + EPS_);
    float sh   = beta[o] - mean * sc;
    float v = fmaf(h[idx], sc, sh);
    outF[idx] = fmaxf(v, 0.0f);
}

extern "C" void kernel_launch(void* const* d_in, const int* in_sizes, int n_in,
                              void* d_out, int out_size, void* d_ws, size_t ws_size,
                              hipStream_t stream) {
    const int*   A     = (const int*)d_in[0];
    const float* x     = (const float*)d_in[1];
    const float* W     = (const float*)d_in[2];
    const float* bias  = (const float*)d_in[3];
    const float* gamma = (const float*)d_in[4];
    const float* beta  = (const float*)d_in[5];
    const int*   dil   = (const int*)d_in[6];

    float* out  = (float*)d_out;
    float* outA = out;                       // B*1*N = 524288 floats (A passthrough)
    float* outF = out + (size_t)B_ * N_;     // B*NOUT = 131072 floats (features)

    float* h    = (float*)d_ws;              // B*NOUT floats = 512 KB
    float* accS = h + (size_t)B_ * NOUT_;    // 128 floats
    float* accQ = accS + NOUT_;              // 128 floats

    k0_zero<<<1, 256, 0, stream>>>(accS);    // zeroes accS+accQ (256 contiguous)
    k1_maskreduce_linear<<<B_, 512, 0, stream>>>(A, x, W, bias, dil, h, accS, accQ, outA);
    k3_norm<<<(B_ * NOUT_) / 256, 256, 0, stream>>>(h, accS, accQ, gamma, beta, outF);
}

// Round 4
// 73.163 us; speedup vs baseline: 1.0419x; 1.0419x over previous
//
#include <hip/hip_runtime.h>

#define B_    1024
#define NIN_  128
#define NOUT_ 128
#define N_    512
#define EPS_  1e-5f

// k0: zero the 256 stat accumulators (ws is poisoned 0xAA; must zero each call)
__global__ __launch_bounds__(256) void k0_zero(float* __restrict__ acc)
{
    acc[threadIdx.x] = 0.0f;
}

// k1: masked reduce over n + fused 128x128 linear + atomic batch-stats
// grid = B_, block = 512
__global__ __launch_bounds__(512) void k1_maskreduce_linear(
    const int* __restrict__ A, const float* __restrict__ x,
    const float* __restrict__ W, const float* __restrict__ bias,
    const int* __restrict__ dil_p, float* __restrict__ h,
    float* __restrict__ accS, float* __restrict__ accQ,
    float* __restrict__ outA)
{
    __shared__ float m[N_];
    __shared__ float s[NIN_];
    const int b = blockIdx.x;
    const int t = threadIdx.x;
    const int dil = *dil_p;

    // Load A row, build mask in LDS, and emit output 0 (A as float)
    const int* Arow = A + (size_t)b * N_;
    float* oA = outA + (size_t)b * N_;
    {
        int n = t;               // 512 threads, N_=512: one element each
        int a = Arow[n];
        m[n] = (a == dil || a == -1) ? 1.0f : 0.0f;
        oA[n] = (float)a;
    }
    __syncthreads();

    const int wave = t >> 6;
    const int lane = t & 63;

    // Per-lane mask registers: lane l covers n in [4l,4l+4) and [256+4l,256+4l+4)
    float mA[4], mB[4];
    #pragma unroll
    for (int j = 0; j < 4; ++j) {
        mA[j] = m[lane * 4 + j];
        mB[j] = m[256 + lane * 4 + j];
    }

    // 8 waves x 16 channels; two fully-contiguous 1KB wave loads per channel
    // (plain cached loads — nt loads measured -35% BW on this chip, R3)
    for (int i = wave; i < NIN_; i += 8) {
        const float* row = x + ((size_t)b * NIN_ + i) * N_;
        float4 v0 = *(const float4*)(row + lane * 4);
        float4 v1 = *(const float4*)(row + 256 + lane * 4);
        float acc = v0.x * mA[0] + v0.y * mA[1] + v0.z * mA[2] + v0.w * mA[3]
                  + v1.x * mB[0] + v1.y * mB[1] + v1.z * mB[2] + v1.w * mB[3];
        #pragma unroll
        for (int off = 32; off > 0; off >>= 1)
            acc += __shfl_xor(acc, off, 64);
        if (lane == 0) s[i] = acc;
    }
    __syncthreads();

    // h[b,o] = bias[o] + sum_i W[o,i] * s[i]; feed batch stats via TCC atomics
    if (t < NOUT_) {
        const float* Wr = W + (size_t)t * NIN_;
        float acc = bias[t];
        #pragma unroll 8
        for (int i = 0; i < NIN_; ++i) acc += Wr[i] * s[i];
        h[(size_t)b * NOUT_ + t] = acc;
        atomicAdd(&accS[t], acc);
        atomicAdd(&accQ[t], acc * acc);
    }
}

// k3: normalize + ReLU, stats computed inline from accumulators
// grid = B_*NOUT_/256, block = 256
__global__ __launch_bounds__(256) void k3_norm(
    const float* __restrict__ h, const float* __restrict__ accS,
    const float* __restrict__ accQ, const float* __restrict__ gamma,
    const float* __restrict__ beta, float* __restrict__ outF)
{
    const int idx = blockIdx.x * 256 + threadIdx.x;
    const int o = idx & (NOUT_ - 1);
    float mean = accS[o] * (1.0f / B_);
    float var  = accQ[o] * (1.0f / B_) - mean * mean;   // biased, training mode
    float sc   = gamma[o] * rsqrtf(var + EPS_);
    float sh   = beta[o] - mean * sc;
    float v = fmaf(h[idx], sc, sh);
    outF[idx] = fmaxf(v, 0.0f);
}

extern "C" void kernel_launch(void* const* d_in, const int* in_sizes, int n_in,
                              void* d_out, int out_size, void* d_ws, size_t ws_size,
                              hipStream_t stream) {
    const int*   A     = (const int*)d_in[0];
    const float* x     = (const float*)d_in[1];
    const float* W     = (const float*)d_in[2];
    const float* bias  = (const float*)d_in[3];
    const float* gamma = (const float*)d_in[4];
    const float* beta  = (const float*)d_in[5];
    const int*   dil   = (const int*)d_in[6];

    float* out  = (float*)d_out;
    float* outA = out;                       // B*1*N = 524288 floats (A passthrough)
    float* outF = out + (size_t)B_ * N_;     // B*NOUT = 131072 floats (features)

    float* h    = (float*)d_ws;              // B*NOUT floats = 512 KB
    float* accS = h + (size_t)B_ * NOUT_;    // 128 floats
    float* accQ = accS + NOUT_;              // 128 floats

    k0_zero<<<1, 256, 0, stream>>>(accS);    // zeroes accS+accQ (256 contiguous)
    k1_maskreduce_linear<<<B_, 512, 0, stream>>>(A, x, W, bias, dil, h, accS, accQ, outA);
    k3_norm<<<(B_ * NOUT_) / 256, 256, 0, stream>>>(h, accS, accQ, gamma, beta, outF);
}

// Round 5
// 54.758 us; speedup vs baseline: 1.3920x; 1.3361x over previous
//
#include <hip/hip_runtime.h>

#define B_    1024
#define NIN_  128
#define NOUT_ 128
#define N_    512
#define EPS_  1e-5f
#define NPART 16          // stat-reduction partial blocks

// k1: masked reduce over n + fused 128x128 linear
// grid = B_, block = 512
__global__ __launch_bounds__(512) void k1_maskreduce_linear(
    const int* __restrict__ A, const float* __restrict__ x,
    const float* __restrict__ W, const float* __restrict__ bias,
    const int* __restrict__ dil_p, float* __restrict__ h,
    float* __restrict__ outA)
{
    __shared__ float m[N_];
    __shared__ float s[NIN_];
    const int b = blockIdx.x;
    const int t = threadIdx.x;
    const int dil = *dil_p;

    // Load A row, build mask in LDS, and emit output 0 (A as float)
    const int* Arow = A + (size_t)b * N_;
    float* oA = outA + (size_t)b * N_;
    {
        int n = t;               // 512 threads, N_=512: one element each
        int a = Arow[n];
        m[n] = (a == dil || a == -1) ? 1.0f : 0.0f;
        oA[n] = (float)a;
    }
    __syncthreads();

    const int wave = t >> 6;
    const int lane = t & 63;

    // Per-lane mask registers: lane l covers n in [4l,4l+4) and [256+4l,256+4l+4)
    float mA[4], mB[4];
    #pragma unroll
    for (int j = 0; j < 4; ++j) {
        mA[j] = m[lane * 4 + j];
        mB[j] = m[256 + lane * 4 + j];
    }

    // 8 waves, 2 adjacent channels per iteration (two independent shuffle
    // chains overlap; 8 iterations). Plain cached loads (nt = -35% BW, R3).
    for (int i = wave * 2; i < NIN_; i += 16) {
        const float* row0 = x + ((size_t)b * NIN_ + i) * N_;
        const float* row1 = row0 + N_;
        float4 a0 = *(const float4*)(row0 + lane * 4);
        float4 a1 = *(const float4*)(row0 + 256 + lane * 4);
        float4 b0 = *(const float4*)(row1 + lane * 4);
        float4 b1 = *(const float4*)(row1 + 256 + lane * 4);
        float acc0 = a0.x * mA[0] + a0.y * mA[1] + a0.z * mA[2] + a0.w * mA[3]
                   + a1.x * mB[0] + a1.y * mB[1] + a1.z * mB[2] + a1.w * mB[3];
        float acc1 = b0.x * mA[0] + b0.y * mA[1] + b0.z * mA[2] + b0.w * mA[3]
                   + b1.x * mB[0] + b1.y * mB[1] + b1.z * mB[2] + b1.w * mB[3];
        #pragma unroll
        for (int off = 32; off > 0; off >>= 1) {
            acc0 += __shfl_xor(acc0, off, 64);
            acc1 += __shfl_xor(acc1, off, 64);
        }
        if (lane == 0) { s[i] = acc0; s[i + 1] = acc1; }
    }
    __syncthreads();

    // h[b,o] = bias[o] + sum_i W[o,i] * s[i]   (threads 0..127; W L2-resident)
    if (t < NOUT_) {
        const float* Wr = W + (size_t)t * NIN_;
        float acc = bias[t];
        #pragma unroll 8
        for (int i = 0; i < NIN_; ++i) acc += Wr[i] * s[i];
        h[(size_t)b * NOUT_ + t] = acc;
    }
}

// k2: coalesced two-level batch-stat partials.
// grid = NPART, block = 256. Block j reduces h[64j .. 64j+64, :].
__global__ __launch_bounds__(256) void k2_partial(
    const float* __restrict__ h, float* __restrict__ pS, float* __restrict__ pQ)
{
    const int j = blockIdx.x;
    const int t = threadIdx.x;
    const int o = t & (NOUT_ - 1);
    const int half = t >> 7;             // 0 or 1: rows [0,32) or [32,64)
    const float* base = h + ((size_t)j * 64 + half * 32) * NOUT_;
    float s = 0.f, q = 0.f;
    #pragma unroll 8
    for (int r = 0; r < 32; ++r) {
        float v = base[(size_t)r * NOUT_ + o];   // consecutive t -> consecutive addr
        s += v; q += v * v;
    }
    __shared__ float ls[2][NOUT_], lq[2][NOUT_];
    ls[half][o] = s; lq[half][o] = q;
    __syncthreads();
    if (t < NOUT_) {
        pS[j * NOUT_ + t] = ls[0][t] + ls[1][t];
        pQ[j * NOUT_ + t] = lq[0][t] + lq[1][t];
    }
}

// k3: stats from partials (L2-hot) + normalize + ReLU
// grid = B_*NOUT_/256, block = 256
__global__ __launch_bounds__(256) void k3_norm(
    const float* __restrict__ h, const float* __restrict__ pS,
    const float* __restrict__ pQ, const float* __restrict__ gamma,
    const float* __restrict__ beta, float* __restrict__ outF)
{
    const int idx = blockIdx.x * 256 + threadIdx.x;
    const int o = idx & (NOUT_ - 1);
    float S = 0.f, Q = 0.f;
    #pragma unroll
    for (int j = 0; j < NPART; ++j) {
        S += pS[j * NOUT_ + o];
        Q += pQ[j * NOUT_ + o];
    }
    float mean = S * (1.0f / B_);
    float var  = Q * (1.0f / B_) - mean * mean;   // biased, training mode
    float sc   = gamma[o] * rsqrtf(var + EPS_);
    float sh   = beta[o] - mean * sc;
    float v = fmaf(h[idx], sc, sh);
    outF[idx] = fmaxf(v, 0.0f);
}

extern "C" void kernel_launch(void* const* d_in, const int* in_sizes, int n_in,
                              void* d_out, int out_size, void* d_ws, size_t ws_size,
                              hipStream_t stream) {
    const int*   A     = (const int*)d_in[0];
    const float* x     = (const float*)d_in[1];
    const float* W     = (const float*)d_in[2];
    const float* bias  = (const float*)d_in[3];
    const float* gamma = (const float*)d_in[4];
    const float* beta  = (const float*)d_in[5];
    const int*   dil   = (const int*)d_in[6];

    float* out  = (float*)d_out;
    float* outA = out;                       // B*1*N = 524288 floats (A passthrough)
    float* outF = out + (size_t)B_ * N_;     // B*NOUT = 131072 floats (features)

    float* h  = (float*)d_ws;                // B*NOUT floats = 512 KB
    float* pS = h + (size_t)B_ * NOUT_;      // NPART*NOUT floats
    float* pQ = pS + NPART * NOUT_;          // NPART*NOUT floats

    k1_maskreduce_linear<<<B_, 512, 0, stream>>>(A, x, W, bias, dil, h, outA);
    k2_partial<<<NPART, 256, 0, stream>>>(h, pS, pQ);
    k3_norm<<<(B_ * NOUT_) / 256, 256, 0, stream>>>(h, pS, pQ, gamma, beta, outF);
}